// Round 4
// baseline (1591.281 us; speedup 1.0000x reference)
//
#include <hip/hip_runtime.h>
#include <stdint.h>

// ---------------- types ----------------
typedef unsigned short u16;
typedef unsigned long long u64;
typedef __attribute__((ext_vector_type(8)))  short  bf16x8;   // 8 bf16 (MFMA A/B frag)
typedef __attribute__((ext_vector_type(8)))  u16    u16x8;
typedef __attribute__((ext_vector_type(4)))  float  f32x4;
typedef __attribute__((ext_vector_type(16))) _Float16 f16x16; // 32B gather chunk

#define MFMA_BF16(a,b,c) __builtin_amdgcn_mfma_f32_16x16x32_bf16((a),(b),(c),0,0,0)

// ---------------- problem constants ----------------
#define BATCH   2048
#define HID     256
#define INP     512
#define FSTEPS  32
#define RSTEPS  3
#define NVF     35            // 32 fwd virtual frames + 3 rev (63,62,61)

// h global buffers: [parity][2048 rows][128 u32] (256 bf16 cols packed in pairs)
static constexpr size_t HROW32 = 128;
static constexpr size_t HPAR32 = (size_t)BATCH * HROW32;

// ---------------- ws layout (bytes) ----------------
static constexpr size_t OFF_CTL  = 0;                                  // 4 KB barrier ctl (zeroed)
static constexpr size_t OFF_H0G  = 4096;                               // 2 MiB (2 parities)
static constexpr size_t OFF_H1G  = OFF_H0G + HPAR32 * 2 * 4;
static constexpr size_t OFF_LAT  = OFF_H1G + HPAR32 * 2 * 4;           // latent fp32 (2048x512)
static constexpr size_t OFF_XP   = OFF_LAT + (size_t)BATCH * 512 * 4;  // xproj fp16, GATHER layout
static constexpr size_t XP_BYTES = (size_t)NVF * BATCH * 1024 * 2;     // [vf][grp][mem][tid][16]
static constexpr size_t OFF_W0XF = OFF_XP + XP_BYTES;                  // Wih0 row-major bf16 [1024][512]
static constexpr size_t OFF_W0XR = OFF_W0XF + (size_t)1024 * 512 * 2;
static constexpr size_t OFF_P0F  = OFF_W0XR + (size_t)1024 * 512 * 2;  // Whh0 frag-packed: 32768 x 16B
static constexpr size_t OFF_P0R  = OFF_P0F + (size_t)32768 * 16;
static constexpr size_t OFF_P1F  = OFF_P0R + (size_t)32768 * 16;       // W1 frag-packed: 65536 x 16B
static constexpr size_t OFF_P1R  = OFF_P1F + (size_t)65536 * 16;
static constexpr size_t OFF_BS0F = OFF_P1R + (size_t)65536 * 16;       // bias sums fp32 [1024]
static constexpr size_t OFF_BS0R = OFF_BS0F + 4096;
static constexpr size_t OFF_BS1F = OFF_BS0R + 4096;
static constexpr size_t OFF_BS1R = OFF_BS1F + 4096;
static constexpr size_t WS_NEED  = OFF_BS1R + 4096;

// ---------------- small helpers ----------------
__device__ __forceinline__ u16 f2bf(float f) {
    unsigned u = __float_as_uint(f);
    unsigned r = (u + 0x7fffu + ((u >> 16) & 1u)) >> 16;
    return (u16)r;
}
__device__ __forceinline__ float sigm(float x) { return 1.0f / (1.0f + __expf(-x)); }
__device__ __forceinline__ float tanh_fast(float x) {
    float a = fabsf(x);
    float e = __expf(-2.0f * a);
    float t = (1.0f - e) / (1.0f + e);
    return x < 0.0f ? -t : t;
}

// 16-WG monotonic group barrier: one RMW + poll >= target. No reset, no release store.
// Per-thread vmcnt(0) before syncthreads guarantees all sc1 h-stores are at the
// coherence point before any thread's arrival RMW becomes visible.
__device__ __forceinline__ void gbar(unsigned* c, unsigned target) {
    asm volatile("s_waitcnt vmcnt(0)" ::: "memory");
    __syncthreads();
    if (threadIdx.x == 0) {
        __hip_atomic_fetch_add(c, 1u, __ATOMIC_RELAXED, __HIP_MEMORY_SCOPE_AGENT);
        while (__hip_atomic_load(c, __ATOMIC_RELAXED, __HIP_MEMORY_SCOPE_AGENT) < target)
            __builtin_amdgcn_s_sleep(1);
    }
    __syncthreads();
}

// LDS h tile: [64 rows][256 bf16], row stride 512B, XOR swizzle on byte bits 4-6
__device__ __forceinline__ bf16x8 ldsA(const char* H, int row, int k) {
    int byte = (row << 9) + (k << 1);
    byte ^= (row & 7) << 4;
    return *(const bf16x8*)(H + byte);
}

// reload 64x256 h tile (32KB) from global parity buffer into LDS; 2 rounds of 8 u64
__device__ __forceinline__ void reload_h(char* Hs, const u64* src, int grp, int tid) {
#pragma unroll
    for (int half = 0; half < 2; ++half) {
        u64 v[8];
#pragma unroll
        for (int i = 0; i < 8; ++i) {
            int idx = tid + ((half * 8 + i) << 8);          // 0..4095
            v[i] = __hip_atomic_load(src + ((size_t)grp * 64 + (idx >> 6)) * 64 + (idx & 63),
                                     __ATOMIC_RELAXED, __HIP_MEMORY_SCOPE_AGENT);
        }
#pragma unroll
        for (int i = 0; i < 8; ++i) {
            int idx = tid + ((half * 8 + i) << 8);
            int row = idx >> 6, cu = idx & 63;
            int byte = (row << 9) + (cu << 3);
            byte ^= (row & 7) << 4;
            *(u64*)(Hs + byte) = v[i];
        }
    }
}

// store 4 h values (rows wv*16+q*4+r, col mem*16+lc) as packed u32 pairs, sc1
__device__ __forceinline__ void store_h4(unsigned* dst32, const float hn[4],
                                         int grp, int wv, int lane, int mem) {
    const int rowbase = grp * 64 + wv * 16 + ((lane >> 4) << 2);
    const int cp = mem * 8 + ((lane & 15) >> 1);
#pragma unroll
    for (int r = 0; r < 4; ++r) {
        float p = __shfl_xor(hn[r], 1);
        if (!(lane & 1)) {
            unsigned w = (unsigned)f2bf(hn[r]) | ((unsigned)f2bf(p) << 16);
            __hip_atomic_store(dst32 + (size_t)(rowbase + r) * HROW32 + cp, w,
                               __ATOMIC_RELAXED, __HIP_MEMORY_SCOPE_AGENT);
        }
    }
}

// ---------------- persistent sequential kernel ----------------
// 512 WGs x 256 thr, 2 blocks/CU. 32 groups x 16 WGs. Group = 64 batch rows,
// member = 16 h-cols. Merged phase: layer1(t-1) + layer0(t) between barriers.
// LDS 64KB static: H0s 32K + H1s 32K. Weights frag-packed in global (L2-resident).
__global__ void __launch_bounds__(256, 2)
lstm_seq(const _Float16* __restrict__ xp,
         const u16* __restrict__ P0f_, const u16* __restrict__ P0r_,
         const u16* __restrict__ P1f_, const u16* __restrict__ P1r_,
         const float* __restrict__ bs1f, const float* __restrict__ bs1r,
         unsigned* __restrict__ h0g, unsigned* __restrict__ h1g,
         float* __restrict__ latent, unsigned* __restrict__ ctl)
{
    __shared__ char lds[65536];
    char* H0s = lds;            // 32768
    char* H1s = lds + 32768;    // 32768

    const int tid = threadIdx.x, wv = tid >> 6, lane = tid & 63;
    const int bid = blockIdx.x;
    const int grp = bid >> 4;        // 0..31  (co-resident pair bid, bid+256 -> different grp)
    const int mem = bid & 15;        // 0..15
    const int hc  = mem * 16 + (lane & 15);
    unsigned* bar = ctl + grp * 32;  // 128B per group
    unsigned bcount = 0;

    for (int dir = 0; dir < 2; ++dir) {
        __syncthreads();
        // zero both LDS h tiles (h0(-1) = h1(-1) = 0)
#pragma unroll
        for (int i = 0; i < 16; ++i)
            *(f32x4*)(lds + (((size_t)tid + (i << 8)) << 4)) = (f32x4){0.f, 0.f, 0.f, 0.f};
        __syncthreads();

        const int nst = dir ? RSTEPS : FSTEPS;
        const bf16x8* P0v = (const bf16x8*)(dir ? P0r_ : P0f_) + (size_t)mem * (8 * 4 * 64);
        const bf16x8* P1v = (const bf16x8*)(dir ? P1r_ : P1f_) + (size_t)mem * (16 * 4 * 64);
        const float* bs1 = dir ? bs1r : bs1f;
        float b1reg[4];
#pragma unroll
        for (int g = 0; g < 4; ++g) b1reg[g] = bs1[g * 256 + hc];

        float c0[4], c1[4];
#pragma unroll
        for (int r = 0; r < 4; ++r) { c0[r] = 0.f; c1[r] = 0.f; }

        for (int t = 0; t <= nst; ++t) {
            const bool do0 = (t < nst);
            const bool do1 = (t > 0);

            // ---- xq: one contiguous 32B load per thread (gather layout) ----
            f16x16 xqv;
            if (do0) {
                const int vf = dir ? (32 + t) : t;
                xqv = *(const f16x16*)(xp +
                    ((((size_t)vf * 32 + grp) * 16 + mem) * 256 + tid) * 16);
            }

            // ======== layer1(t-1): acc1 = [H0s | H1s] @ W1^T ========
            f32x4 acc1 = (f32x4){0.f, 0.f, 0.f, 0.f};   // per gate accumulated below
            f32x4 a1g[4];
#pragma unroll
            for (int g = 0; g < 4; ++g) a1g[g] = (f32x4){0.f, 0.f, 0.f, 0.f};
            if (do1) {
#pragma unroll
                for (int kc = 0; kc < 16; ++kc) {
                    const char* Hs = (kc < 8) ? H0s : H1s;
                    const int kk = (kc & 7) * 32 + ((lane >> 4) << 3);
                    bf16x8 a = ldsA(Hs, wv * 16 + (lane & 15), kk);
#pragma unroll
                    for (int g = 0; g < 4; ++g) {
                        bf16x8 b = P1v[(kc * 4 + g) * 64 + lane];
                        a1g[g] = MFMA_BF16(a, b, a1g[g]);
                    }
                }
            }
            (void)acc1;

            // ======== layer0(t): acc0 = H0s @ Whh0^T ========
            f32x4 a0g[4];
#pragma unroll
            for (int g = 0; g < 4; ++g) a0g[g] = (f32x4){0.f, 0.f, 0.f, 0.f};
            if (do0 && t > 0) {   // at t==0 h0prev==0 -> acc stays 0
#pragma unroll
                for (int kc = 0; kc < 8; ++kc) {
                    const int kk = kc * 32 + ((lane >> 4) << 3);
                    bf16x8 a = ldsA(H0s, wv * 16 + (lane & 15), kk);
#pragma unroll
                    for (int g = 0; g < 4; ++g) {
                        bf16x8 b = P0v[(kc * 4 + g) * 64 + lane];
                        a0g[g] = MFMA_BF16(a, b, a0g[g]);
                    }
                }
            }

            // ---- epilogue0: LSTM cell layer0, store h0(t) ----
            if (do0) {
                float hn0[4];
#pragma unroll
                for (int r = 0; r < 4; ++r) {
                    float gi = a0g[0][r] + (float)xqv[0 * 4 + r];
                    float gf = a0g[1][r] + (float)xqv[1 * 4 + r];
                    float gg = a0g[2][r] + (float)xqv[2 * 4 + r];
                    float go = a0g[3][r] + (float)xqv[3 * 4 + r];
                    float cn = sigm(gf) * c0[r] + sigm(gi) * tanh_fast(gg);
                    c0[r] = cn;
                    hn0[r] = sigm(go) * tanh_fast(cn);
                }
                store_h4(h0g + (size_t)(t & 1) * HPAR32, hn0, grp, wv, lane, mem);
            }

            // ---- epilogue1: LSTM cell layer1, store h1(t-1) / latent ----
            if (do1) {
                float hn1[4];
#pragma unroll
                for (int r = 0; r < 4; ++r) {
                    float gi = a1g[0][r] + b1reg[0];
                    float gf = a1g[1][r] + b1reg[1];
                    float gg = a1g[2][r] + b1reg[2];
                    float go = a1g[3][r] + b1reg[3];
                    float cn = sigm(gf) * c1[r] + sigm(gi) * tanh_fast(gg);
                    c1[r] = cn;
                    hn1[r] = sigm(go) * tanh_fast(cn);
                }
                if (t < nst) {
                    store_h4(h1g + (size_t)((t + 1) & 1) * HPAR32, hn1, grp, wv, lane, mem);
                } else {
                    const int rowbase = grp * 64 + wv * 16 + ((lane >> 4) << 2);
#pragma unroll
                    for (int r = 0; r < 4; ++r)
                        latent[(size_t)(rowbase + r) * 512 + dir * 256 + hc] = hn1[r];
                }
            }

            // ---- barrier + reload (skip after tail) ----
            if (t < nst) {
                ++bcount;
                gbar(bar, bcount * 16u);
                reload_h(H0s, (const u64*)(h0g + (size_t)(t & 1) * HPAR32), grp, tid);
                if (t > 0)
                    reload_h(H1s, (const u64*)(h1g + (size_t)((t + 1) & 1) * HPAR32), grp, tid);
                __syncthreads();
            }
        }
    }
}

// ---------------- x-projection GEMM (gather-layout output) ----------------
__global__ void __launch_bounds__(256)
xproj_gemm(const float* __restrict__ xs,
           const u16* __restrict__ W0xf, const u16* __restrict__ W0xr,
           const float* __restrict__ bs0f, const float* __restrict__ bs0r,
           _Float16* __restrict__ xp)
{
    __shared__ char As[16384];
    __shared__ char Bs[16384];
    const int tid = threadIdx.x, wv = tid >> 6, lane = tid & 63;
    const int phys = blockIdx.x;
    const int xcd = phys & 7, idx = phys >> 3;
    const int mt = xcd * 70 + (idx >> 3);     // 0..559
    const int nt = idx & 7;
    const int vf = mt >> 4;
    const int dirr = (vf >= 32);
    const int frame = dirr ? (95 - vf) : (30 + vf);
    const int brow = (mt & 15) * 128;
    const u16* Wp = (dirr ? W0xr : W0xf) + (size_t)nt * 128 * 512;
    const float* bs = dirr ? bs0r : bs0f;

    float breg[8];
#pragma unroll
    for (int n = 0; n < 8; ++n) breg[n] = bs[nt * 128 + n * 16 + (lane & 15)];

    f32x4 acc[8][2];
#pragma unroll
    for (int n = 0; n < 8; ++n) { acc[n][0] = (f32x4){0.f,0.f,0.f,0.f}; acc[n][1] = (f32x4){0.f,0.f,0.f,0.f}; }

    const int ar = tid >> 1, akoff = (tid & 1) * 32;
    const float* asrc0 = xs + ((size_t)(brow + ar) * 64 + frame) * 512 + akoff;

    for (int c = 0; c < 8; ++c) {
        {   // stage A: 128 rows x 64 k, fp32 -> bf16
            const float* s = asrc0 + c * 64;
            u16x8 o[4];
#pragma unroll
            for (int j2 = 0; j2 < 4; ++j2) {
                float4 f0 = *(const float4*)(s + j2 * 8);
                float4 f1 = *(const float4*)(s + j2 * 8 + 4);
                u16x8 o_;
                o_[0] = f2bf(f0.x); o_[1] = f2bf(f0.y); o_[2] = f2bf(f0.z); o_[3] = f2bf(f0.w);
                o_[4] = f2bf(f1.x); o_[5] = f2bf(f1.y); o_[6] = f2bf(f1.z); o_[7] = f2bf(f1.w);
                o[j2] = o_;
            }
#pragma unroll
            for (int j2 = 0; j2 < 4; ++j2) {
                int k = akoff + j2 * 8;
                int byte = (ar << 7) + (k << 1); byte ^= (ar & 7) << 4;
                *(u16x8*)(As + byte) = o[j2];
            }
        }
#pragma unroll
        for (int i = 0; i < 4; ++i) {   // stage B: 128 rows x 64 k
            int u = tid + i * 256;
            int ns = u >> 3, c8 = (u & 7) << 3;
            u16x8 v = *(const u16x8*)(Wp + (size_t)ns * 512 + c * 64 + c8);
            int byte = (ns << 7) + (c8 << 1); byte ^= (ns & 7) << 4;
            *(u16x8*)(Bs + byte) = v;
        }
        __syncthreads();
#pragma unroll
        for (int kk = 0; kk < 2; ++kk) {
            int kin = kk * 32 + (lane >> 4) * 8;
            bf16x8 a0, a1;
            int row = wv * 32 + (lane & 15);
            int byte = (row << 7) + (kin << 1); byte ^= (row & 7) << 4;
            a0 = *(const bf16x8*)(As + byte);
            int row1 = row + 16;
            byte = (row1 << 7) + (kin << 1); byte ^= (row1 & 7) << 4;
            a1 = *(const bf16x8*)(As + byte);
#pragma unroll
            for (int n = 0; n < 8; ++n) {
                int ns = n * 16 + (lane & 15);
                int bb = (ns << 7) + (kin << 1); bb ^= (ns & 7) << 4;
                bf16x8 bf_ = *(const bf16x8*)(Bs + bb);
                acc[n][0] = MFMA_BF16(a0, bf_, acc[n][0]);
                acc[n][1] = MFMA_BF16(a1, bf_, acc[n][1]);
            }
        }
        __syncthreads();
    }
    // epilogue: write gather layout [vf][grp][mem][ctid][g*4+r]
#pragma unroll
    for (int n = 0; n < 8; ++n)
#pragma unroll
        for (int m = 0; m < 2; ++m)
#pragma unroll
            for (int r = 0; r < 4; ++r) {
                int vm  = mt * 128 + wv * 32 + m * 16 + ((lane >> 4) << 2) + r;
                int col = nt * 128 + n * 16 + (lane & 15);
                int b2  = vm & 2047, vf2 = vm >> 11;
                int grp2 = b2 >> 6, rr = b2 & 63;
                int ctid = ((rr >> 4) << 6) + (((rr >> 2) & 3) << 4) + (col & 15);
                int mem2 = (col >> 4) & 15, g2 = col >> 8;
                size_t o = ((((size_t)vf2 * 32 + grp2) * 16 + mem2) * 256 + ctid) * 16
                           + (g2 << 2) + (rr & 3);
                xp[o] = (_Float16)(acc[n][m][r] + breg[n]);
            }
}

// ---------------- prep kernels ----------------
__global__ void pack_w(const float* __restrict__ Wa, int da,
                       const float* __restrict__ bi, const float* __restrict__ bh,
                       u16* __restrict__ Wout, float* __restrict__ bout)
{
    int total = 1024 * da;
    int gt = blockIdx.x * blockDim.x + threadIdx.x;
    int stride = gridDim.x * blockDim.x;
    for (int i = gt; i < total; i += stride) Wout[i] = f2bf(Wa[i]);
    if (bout && gt < 1024) bout[gt] = bi[gt] + bh[gt];
}

// fragment-ordered pack: unit u (16B) -> l=u&63, g=(u>>6)&3, kc, mem;
// row = g*256 + mem*16 + (l&15); k0 = kc*32 + (l>>4)*8;  K = 32*nkc = da+db
__global__ void pack_frag(const float* __restrict__ Wa, int da,
                          const float* __restrict__ Wb, int db,
                          int nkc, u16* __restrict__ out,
                          const float* __restrict__ bi, const float* __restrict__ bh,
                          float* __restrict__ bout)
{
    int total = 16 * nkc * 4 * 64;
    int gt = blockIdx.x * blockDim.x + threadIdx.x;
    int stride = gridDim.x * blockDim.x;
    for (int u = gt; u < total; u += stride) {
        int l = u & 63;
        int t1 = u >> 6;
        int g = t1 & 3;
        int t2 = t1 >> 2;
        int kc = t2 % nkc;
        int mem = t2 / nkc;
        int row = g * 256 + mem * 16 + (l & 15);
        int k0 = kc * 32 + ((l >> 4) << 3);
        u16x8 o;
#pragma unroll
        for (int j = 0; j < 8; ++j) {
            int k = k0 + j;
            float v = (k < da) ? Wa[(size_t)row * da + k] : Wb[(size_t)row * db + (k - da)];
            o[j] = f2bf(v);
        }
        *(u16x8*)(out + (size_t)u * 8) = o;
    }
    if (bout && gt < 1024) bout[gt] = bi[gt] + bh[gt];
}

// ---------------- final linear ----------------
__global__ void final_linear(const float* __restrict__ latent, const float* __restrict__ W3,
                             const float* __restrict__ b3, float* __restrict__ out)
{
    int idx = blockIdx.x * blockDim.x + threadIdx.x;
    if (idx >= BATCH * 10) return;
    int bb = idx / 10, c = idx - bb * 10;
    const float* lrow = latent + (size_t)bb * 512;
    const float* wrow = W3 + (size_t)c * 512;
    float s = b3[c];
#pragma unroll 4
    for (int k = 0; k < 512; k += 4) {
        float4 lv = *(const float4*)(lrow + k);
        float4 wv = *(const float4*)(wrow + k);
        s += lv.x * wv.x + lv.y * wv.y + lv.z * wv.z + lv.w * wv.w;
    }
    out[idx] = s;
}

// ---------------- launch ----------------
extern "C" void kernel_launch(void* const* d_in, const int* in_sizes, int n_in,
                              void* d_out, int out_size, void* d_ws, size_t ws_size,
                              hipStream_t stream)
{
    (void)in_sizes; (void)n_in; (void)out_size;
    if (ws_size < WS_NEED) return;   // leaves d_out poisoned -> diagnosable as ws shortfall

    const float* xs     = (const float*)d_in[0];
    const float* Wih_f0 = (const float*)d_in[1];
    const float* Whh_f0 = (const float*)d_in[2];
    const float* bih_f0 = (const float*)d_in[3];
    const float* bhh_f0 = (const float*)d_in[4];
    const float* Wih_f1 = (const float*)d_in[5];
    const float* Whh_f1 = (const float*)d_in[6];
    const float* bih_f1 = (const float*)d_in[7];
    const float* bhh_f1 = (const float*)d_in[8];
    const float* Wih_r0 = (const float*)d_in[9];
    const float* Whh_r0 = (const float*)d_in[10];
    const float* bih_r0 = (const float*)d_in[11];
    const float* bhh_r0 = (const float*)d_in[12];
    const float* Wih_r1 = (const float*)d_in[13];
    const float* Whh_r1 = (const float*)d_in[14];
    const float* bih_r1 = (const float*)d_in[15];
    const float* bhh_r1 = (const float*)d_in[16];
    const float* W3     = (const float*)d_in[17];
    const float* b3     = (const float*)d_in[18];

    char* ws = (char*)d_ws;
    unsigned* ctl = (unsigned*)(ws + OFF_CTL);
    unsigned* h0g = (unsigned*)(ws + OFF_H0G);
    unsigned* h1g = (unsigned*)(ws + OFF_H1G);
    float* latent = (float*)(ws + OFF_LAT);
    _Float16* xp  = (_Float16*)(ws + OFF_XP);
    u16* W0xf = (u16*)(ws + OFF_W0XF);
    u16* W0xr = (u16*)(ws + OFF_W0XR);
    u16* P0f  = (u16*)(ws + OFF_P0F);
    u16* P0r  = (u16*)(ws + OFF_P0R);
    u16* P1f  = (u16*)(ws + OFF_P1F);
    u16* P1r  = (u16*)(ws + OFF_P1R);
    float* bs0f = (float*)(ws + OFF_BS0F);
    float* bs0r = (float*)(ws + OFF_BS0R);
    float* bs1f = (float*)(ws + OFF_BS1F);
    float* bs1r = (float*)(ws + OFF_BS1R);

    hipMemsetAsync(ctl, 0, 4096, stream);   // barrier counters only

    pack_w<<<256, 256, 0, stream>>>(Wih_f0, 512, bih_f0, bhh_f0, W0xf, bs0f);
    pack_w<<<256, 256, 0, stream>>>(Wih_r0, 512, bih_r0, bhh_r0, W0xr, bs0r);
    pack_frag<<<64, 256, 0, stream>>>(Whh_f0, 256, Whh_f0, 0, 8,  P0f, nullptr, nullptr, nullptr);
    pack_frag<<<64, 256, 0, stream>>>(Whh_r0, 256, Whh_r0, 0, 8,  P0r, nullptr, nullptr, nullptr);
    pack_frag<<<64, 256, 0, stream>>>(Wih_f1, 256, Whh_f1, 256, 16, P1f, bih_f1, bhh_f1, bs1f);
    pack_frag<<<64, 256, 0, stream>>>(Wih_r1, 256, Whh_r1, 256, 16, P1r, bih_r1, bhh_r1, bs1r);

    xproj_gemm<<<4480, 256, 0, stream>>>(xs, W0xf, W0xr, bs0f, bs0r, xp);

    lstm_seq<<<512, 256, 0, stream>>>(xp, P0f, P0r, P1f, P1r, bs1f, bs1r,
                                      h0g, h1g, latent, ctl);

    final_linear<<<80, 256, 0, stream>>>(latent, W3, b3, (float*)d_out);
}

// Round 5
// 1168.752 us; speedup vs baseline: 1.3615x; 1.3615x over previous
//
#include <hip/hip_runtime.h>
#include <stdint.h>

// ---------------- types ----------------
typedef unsigned short u16;
typedef unsigned long long u64;
typedef __attribute__((ext_vector_type(8)))  short  bf16x8;   // 8 bf16 (MFMA A/B frag)
typedef __attribute__((ext_vector_type(8)))  u16    u16x8;
typedef __attribute__((ext_vector_type(4)))  float  f32x4;
typedef __attribute__((ext_vector_type(16))) _Float16 f16x16; // 32B chunk

#define MFMA_BF16(a,b,c) __builtin_amdgcn_mfma_f32_16x16x32_bf16((a),(b),(c),0,0,0)

// ---------------- problem constants ----------------
#define BATCH   2048
#define HID     256
#define INP     512
#define FSTEPS  32
#define RSTEPS  3
#define NVF     35            // 32 fwd virtual frames + 3 rev (63,62,61)

// h global buffers: [parity][2048 rows][128 u32] (256 bf16 cols packed in pairs)
static constexpr size_t HROW32 = 128;
static constexpr size_t HPAR32 = (size_t)BATCH * HROW32;

// ---------------- ws layout (bytes) ----------------
static constexpr size_t OFF_CTL  = 0;                                  // 4 KB flag lines (zeroed)
static constexpr size_t OFF_H0G  = 4096;                               // 2 MiB (2 parities)
static constexpr size_t OFF_H1G  = OFF_H0G + HPAR32 * 2 * 4;
static constexpr size_t OFF_LAT  = OFF_H1G + HPAR32 * 2 * 4;           // latent fp32 (2048x512)
static constexpr size_t OFF_XP   = OFF_LAT + (size_t)BATCH * 512 * 4;  // xproj fp16, gather layout
static constexpr size_t XP_BYTES = (size_t)NVF * BATCH * 1024 * 2;     // [vf][rb64][m16][lane64][32]
static constexpr size_t OFF_W0XF = OFF_XP + XP_BYTES;                  // Wih0 row-major bf16 [1024][512]
static constexpr size_t OFF_W0XR = OFF_W0XF + (size_t)1024 * 512 * 2;
static constexpr size_t OFF_P0F  = OFF_W0XR + (size_t)1024 * 512 * 2;  // Whh0 frag-packed: 32768 x 16B
static constexpr size_t OFF_P0R  = OFF_P0F + (size_t)32768 * 16;
static constexpr size_t OFF_P1F  = OFF_P0R + (size_t)32768 * 16;       // W1 frag-packed: 65536 x 16B
static constexpr size_t OFF_P1R  = OFF_P1F + (size_t)65536 * 16;
static constexpr size_t OFF_BS0F = OFF_P1R + (size_t)65536 * 16;       // bias sums fp32 [1024]
static constexpr size_t OFF_BS0R = OFF_BS0F + 4096;
static constexpr size_t OFF_BS1F = OFF_BS0R + 4096;
static constexpr size_t OFF_BS1R = OFF_BS1F + 4096;
static constexpr size_t WS_NEED  = OFF_BS1R + 4096;

// ---------------- small helpers ----------------
__device__ __forceinline__ u16 f2bf(float f) {
    unsigned u = __float_as_uint(f);
    unsigned r = (u + 0x7fffu + ((u >> 16) & 1u)) >> 16;
    return (u16)r;
}
__device__ __forceinline__ float sigm(float x) { return 1.0f / (1.0f + __expf(-x)); }
__device__ __forceinline__ float tanh_fast(float x) {
    float a = fabsf(x);
    float e = __expf(-2.0f * a);
    float t = (1.0f - e) / (1.0f + e);
    return x < 0.0f ? -t : t;
}

// coherence-point 16B A-frag load (2 x u64 relaxed AGENT atomics, known-good codegen)
__device__ __forceinline__ bf16x8 load_frag_sc(const char* p) {
    u64 a = __hip_atomic_load((const u64*)p,       __ATOMIC_RELAXED, __HIP_MEMORY_SCOPE_AGENT);
    u64 b = __hip_atomic_load((const u64*)(p + 8), __ATOMIC_RELAXED, __HIP_MEMORY_SCOPE_AGENT);
    union { u64 q[2]; bf16x8 v; } u;
    u.q[0] = a; u.q[1] = b;
    return u.v;
}

// ---------------- persistent sequential kernel ----------------
// 256 blocks x 256 thr, 1 block/CU. Unit = one wave: unit = wv*256 + bid.
// rb = unit>>4 (row-group: 32 batch rows), m = unit&15 = bid&15 (64 gate-cols).
// Group = 16 units sharing rb; sync via per-unit monotonic flag line (64B), no RMW.
// All 4 waves of a CU share weight slice m -> weights L2/L1-resident (normal loads).
// h-state exchanged via sc1 (AGENT atomic) stores/loads. NO LDS, NO __syncthreads.
__global__ void __launch_bounds__(256, 1)
lstm_seq(const _Float16* __restrict__ xp,
         const u16* __restrict__ P0f_, const u16* __restrict__ P0r_,
         const u16* __restrict__ P1f_, const u16* __restrict__ P1r_,
         const float* __restrict__ bs1f, const float* __restrict__ bs1r,
         unsigned* __restrict__ h0g, unsigned* __restrict__ h1g,
         float* __restrict__ latent, unsigned* __restrict__ ctl)
{
    const int tid = threadIdx.x, wv = tid >> 6, lane = tid & 63;
    const int unit = wv * 256 + blockIdx.x;
    const int rb = unit >> 4;            // 0..63
    const int m  = unit & 15;            // 0..15 (== blockIdx.x & 15)
    const int hc = m * 16 + (lane & 15);
    const int row0  = rb * 32 + (lane & 15);   // A-frag row (per lane)
    const int klane = lane >> 4;               // k-segment 0..3
    unsigned* flags = ctl + rb * 16;           // 64B line per group
    unsigned steps = 0;

    for (int dir = 0; dir < 2; ++dir) {
        const int nst = dir ? RSTEPS : FSTEPS;
        const bf16x8* P0v = (const bf16x8*)(dir ? P0r_ : P0f_) + (size_t)m * (8 * 4 * 64);
        const bf16x8* P1v = (const bf16x8*)(dir ? P1r_ : P1f_) + (size_t)m * (16 * 4 * 64);
        const float* bs1 = dir ? bs1r : bs1f;
        float b1reg[4];
#pragma unroll
        for (int g = 0; g < 4; ++g) b1reg[g] = bs1[g * 256 + hc];

        float c0[2][4], c1[2][4];
#pragma unroll
        for (int Mt = 0; Mt < 2; ++Mt)
#pragma unroll
            for (int r = 0; r < 4; ++r) { c0[Mt][r] = 0.f; c1[Mt][r] = 0.f; }

        for (int t = 0; t <= nst; ++t) {
            const bool haveH0 = (t >= 1);
            const bool haveH1 = (t >= 2);
            const bool do0 = (t < nst);
            const bool do1 = (t >= 1);

            // ---- xq: 64B contiguous per lane (issue before any dependent work) ----
            f16x16 xqa, xqb;
            if (do0) {
                const int vf = dir ? (32 + t) : t;
                const f16x16* xq16 = (const f16x16*)(xp +
                    ((((size_t)vf * 64 + rb) * 16 + m) * 64 + lane) * 32);
                xqa = xq16[0];   // Mt=0: [g*4+rr]
                xqb = xq16[1];   // Mt=1
            }

            // ---- A-frag loads (sc1): h0(t-1), h1(t-2) ----
            bf16x8 a0f[2][8], a1f[2][8];
            if (haveH0) {
                const char* hb = (const char*)(h0g + (size_t)((t + 1) & 1) * HPAR32);
#pragma unroll
                for (int Mt = 0; Mt < 2; ++Mt)
#pragma unroll
                    for (int kc = 0; kc < 8; ++kc)
                        a0f[Mt][kc] = load_frag_sc(hb + (size_t)(row0 + Mt * 16) * 512
                                                      + kc * 64 + klane * 16);
            }
            if (haveH1) {
                const char* hb = (const char*)(h1g + (size_t)(t & 1) * HPAR32);
#pragma unroll
                for (int Mt = 0; Mt < 2; ++Mt)
#pragma unroll
                    for (int kc = 0; kc < 8; ++kc)
                        a1f[Mt][kc] = load_frag_sc(hb + (size_t)(row0 + Mt * 16) * 512
                                                      + kc * 64 + klane * 16);
            }

            // ======== layer1(t-1): acc1 = [h0cur | h1prev] @ W1^T ========
            if (do1) {
                f32x4 acc1[2][4];
#pragma unroll
                for (int Mt = 0; Mt < 2; ++Mt)
#pragma unroll
                    for (int g = 0; g < 4; ++g) acc1[Mt][g] = (f32x4){0.f,0.f,0.f,0.f};
#pragma unroll
                for (int kc = 0; kc < 8; ++kc) {
#pragma unroll
                    for (int g = 0; g < 4; ++g) {
                        bf16x8 b = P1v[(kc * 4 + g) * 64 + lane];
                        acc1[0][g] = MFMA_BF16(a0f[0][kc], b, acc1[0][g]);
                        acc1[1][g] = MFMA_BF16(a0f[1][kc], b, acc1[1][g]);
                    }
                }
                if (haveH1) {
#pragma unroll
                    for (int kc = 0; kc < 8; ++kc) {
#pragma unroll
                        for (int g = 0; g < 4; ++g) {
                            bf16x8 b = P1v[((kc + 8) * 4 + g) * 64 + lane];
                            acc1[0][g] = MFMA_BF16(a1f[0][kc], b, acc1[0][g]);
                            acc1[1][g] = MFMA_BF16(a1f[1][kc], b, acc1[1][g]);
                        }
                    }
                }
                // epilogue1: LSTM cell, h1(t-1) stores / latent at tail
#pragma unroll
                for (int Mt = 0; Mt < 2; ++Mt) {
                    float hn[4];
#pragma unroll
                    for (int r = 0; r < 4; ++r) {
                        float gi = acc1[Mt][0][r] + b1reg[0];
                        float gf = acc1[Mt][1][r] + b1reg[1];
                        float gg = acc1[Mt][2][r] + b1reg[2];
                        float go = acc1[Mt][3][r] + b1reg[3];
                        float cn = sigm(gf) * c1[Mt][r] + sigm(gi) * tanh_fast(gg);
                        c1[Mt][r] = cn;
                        hn[r] = sigm(go) * tanh_fast(cn);
                    }
                    const int rowbase = rb * 32 + Mt * 16 + ((lane >> 4) << 2);
                    if (t < nst) {
                        unsigned* dst = h1g + (size_t)((t + 1) & 1) * HPAR32;  // parity (t-1)&1
                        const int cp = m * 8 + ((lane & 15) >> 1);
#pragma unroll
                        for (int r = 0; r < 4; ++r) {
                            float p = __shfl_xor(hn[r], 1);
                            if (!(lane & 1)) {
                                unsigned w = (unsigned)f2bf(hn[r]) | ((unsigned)f2bf(p) << 16);
                                __hip_atomic_store(dst + (size_t)(rowbase + r) * HROW32 + cp, w,
                                                   __ATOMIC_RELAXED, __HIP_MEMORY_SCOPE_AGENT);
                            }
                        }
                    } else {
#pragma unroll
                        for (int r = 0; r < 4; ++r)
                            latent[(size_t)(rowbase + r) * 512 + dir * 256 + hc] = hn[r];
                    }
                }
            }

            // ======== layer0(t): acc0 = h0prev @ Whh0^T ; cell; h0(t) stores ========
            if (do0) {
                f32x4 acc0[2][4];
#pragma unroll
                for (int Mt = 0; Mt < 2; ++Mt)
#pragma unroll
                    for (int g = 0; g < 4; ++g) acc0[Mt][g] = (f32x4){0.f,0.f,0.f,0.f};
                if (haveH0) {
#pragma unroll
                    for (int kc = 0; kc < 8; ++kc) {
#pragma unroll
                        for (int g = 0; g < 4; ++g) {
                            bf16x8 b = P0v[(kc * 4 + g) * 64 + lane];
                            acc0[0][g] = MFMA_BF16(a0f[0][kc], b, acc0[0][g]);
                            acc0[1][g] = MFMA_BF16(a0f[1][kc], b, acc0[1][g]);
                        }
                    }
                }
#pragma unroll
                for (int Mt = 0; Mt < 2; ++Mt) {
                    const f16x16 xq = Mt ? xqb : xqa;
                    float hn[4];
#pragma unroll
                    for (int r = 0; r < 4; ++r) {
                        float gi = acc0[Mt][0][r] + (float)xq[0 * 4 + r];
                        float gf = acc0[Mt][1][r] + (float)xq[1 * 4 + r];
                        float gg = acc0[Mt][2][r] + (float)xq[2 * 4 + r];
                        float go = acc0[Mt][3][r] + (float)xq[3 * 4 + r];
                        float cn = sigm(gf) * c0[Mt][r] + sigm(gi) * tanh_fast(gg);
                        c0[Mt][r] = cn;
                        hn[r] = sigm(go) * tanh_fast(cn);
                    }
                    unsigned* dst = h0g + (size_t)(t & 1) * HPAR32;
                    const int rowbase = rb * 32 + Mt * 16 + ((lane >> 4) << 2);
                    const int cp = m * 8 + ((lane & 15) >> 1);
#pragma unroll
                    for (int r = 0; r < 4; ++r) {
                        float p = __shfl_xor(hn[r], 1);
                        if (!(lane & 1)) {
                            unsigned w = (unsigned)f2bf(hn[r]) | ((unsigned)f2bf(p) << 16);
                            __hip_atomic_store(dst + (size_t)(rowbase + r) * HROW32 + cp, w,
                                               __ATOMIC_RELAXED, __HIP_MEMORY_SCOPE_AGENT);
                        }
                    }
                }
            }

            // ---- per-group wave barrier (skip after tail iteration) ----
            if (t < nst) {
                ++steps;
                asm volatile("s_waitcnt vmcnt(0)" ::: "memory");  // h stores + reads at L3
                if (lane == 0)
                    __hip_atomic_store(flags + m, steps, __ATOMIC_RELAXED, __HIP_MEMORY_SCOPE_AGENT);
                for (;;) {
                    unsigned v = steps;
                    if (lane < 16)
                        v = __hip_atomic_load(flags + lane, __ATOMIC_RELAXED, __HIP_MEMORY_SCOPE_AGENT);
                    if (__all((int)(v >= steps))) break;
                    __builtin_amdgcn_s_sleep(1);
                }
                __builtin_amdgcn_sched_barrier(0);   // no compiler motion across the barrier
            }
        }
    }
}

// ---------------- x-projection GEMM (gather-layout output) ----------------
__global__ void __launch_bounds__(256)
xproj_gemm(const float* __restrict__ xs,
           const u16* __restrict__ W0xf, const u16* __restrict__ W0xr,
           const float* __restrict__ bs0f, const float* __restrict__ bs0r,
           _Float16* __restrict__ xp)
{
    __shared__ char As[16384];
    __shared__ char Bs[16384];
    const int tid = threadIdx.x, wv = tid >> 6, lane = tid & 63;
    const int phys = blockIdx.x;
    const int xcd = phys & 7, idx = phys >> 3;
    const int mt = xcd * 70 + (idx >> 3);     // 0..559
    const int nt = idx & 7;
    const int vf = mt >> 4;
    const int dirr = (vf >= 32);
    const int frame = dirr ? (95 - vf) : (30 + vf);
    const int brow = (mt & 15) * 128;
    const u16* Wp = (dirr ? W0xr : W0xf) + (size_t)nt * 128 * 512;
    const float* bs = dirr ? bs0r : bs0f;

    float breg[8];
#pragma unroll
    for (int n = 0; n < 8; ++n) breg[n] = bs[nt * 128 + n * 16 + (lane & 15)];

    f32x4 acc[8][2];
#pragma unroll
    for (int n = 0; n < 8; ++n) { acc[n][0] = (f32x4){0.f,0.f,0.f,0.f}; acc[n][1] = (f32x4){0.f,0.f,0.f,0.f}; }

    const int ar = tid >> 1, akoff = (tid & 1) * 32;
    const float* asrc0 = xs + ((size_t)(brow + ar) * 64 + frame) * 512 + akoff;

    for (int c = 0; c < 8; ++c) {
        {   // stage A: 128 rows x 64 k, fp32 -> bf16
            const float* s = asrc0 + c * 64;
            u16x8 o[4];
#pragma unroll
            for (int j2 = 0; j2 < 4; ++j2) {
                float4 f0 = *(const float4*)(s + j2 * 8);
                float4 f1 = *(const float4*)(s + j2 * 8 + 4);
                u16x8 o_;
                o_[0] = f2bf(f0.x); o_[1] = f2bf(f0.y); o_[2] = f2bf(f0.z); o_[3] = f2bf(f0.w);
                o_[4] = f2bf(f1.x); o_[5] = f2bf(f1.y); o_[6] = f2bf(f1.z); o_[7] = f2bf(f1.w);
                o[j2] = o_;
            }
#pragma unroll
            for (int j2 = 0; j2 < 4; ++j2) {
                int k = akoff + j2 * 8;
                int byte = (ar << 7) + (k << 1); byte ^= (ar & 7) << 4;
                *(u16x8*)(As + byte) = o[j2];
            }
        }
#pragma unroll
        for (int i = 0; i < 4; ++i) {   // stage B: 128 rows x 64 k
            int u = tid + i * 256;
            int ns = u >> 3, c8 = (u & 7) << 3;
            u16x8 v = *(const u16x8*)(Wp + (size_t)ns * 512 + c * 64 + c8);
            int byte = (ns << 7) + (c8 << 1); byte ^= (ns & 7) << 4;
            *(u16x8*)(Bs + byte) = v;
        }
        __syncthreads();
#pragma unroll
        for (int kk = 0; kk < 2; ++kk) {
            int kin = kk * 32 + (lane >> 4) * 8;
            bf16x8 a0, a1;
            int row = wv * 32 + (lane & 15);
            int byte = (row << 7) + (kin << 1); byte ^= (row & 7) << 4;
            a0 = *(const bf16x8*)(As + byte);
            int row1 = row + 16;
            byte = (row1 << 7) + (kin << 1); byte ^= (row1 & 7) << 4;
            a1 = *(const bf16x8*)(As + byte);
#pragma unroll
            for (int n = 0; n < 8; ++n) {
                int ns = n * 16 + (lane & 15);
                int bb = (ns << 7) + (kin << 1); bb ^= (ns & 7) << 4;
                bf16x8 bf_ = *(const bf16x8*)(Bs + bb);
                acc[n][0] = MFMA_BF16(a0, bf_, acc[n][0]);
                acc[n][1] = MFMA_BF16(a1, bf_, acc[n][1]);
            }
        }
        __syncthreads();
    }
    // epilogue: gather layout [vf][rb64][m16][lane64][Mt*16+g*4+rr]
#pragma unroll
    for (int n = 0; n < 8; ++n)
#pragma unroll
        for (int mm = 0; mm < 2; ++mm)
#pragma unroll
            for (int r = 0; r < 4; ++r) {
                int vm  = mt * 128 + wv * 32 + mm * 16 + ((lane >> 4) << 2) + r;
                int col = nt * 128 + n * 16 + (lane & 15);
                int vf2 = vm >> 11, brow2 = vm & 2047;
                int rb2 = brow2 >> 5, Mt2 = (brow2 >> 4) & 1, sub = brow2 & 15;
                int lane2 = ((sub >> 2) << 4) + (col & 15);
                int idx16 = Mt2 * 16 + (col >> 8) * 4 + (sub & 3);
                size_t o = ((((size_t)vf2 * 64 + rb2) * 16 + ((col >> 4) & 15)) * 64 + lane2) * 32
                           + idx16;
                xp[o] = (_Float16)(acc[n][mm][r] + breg[n]);
            }
}

// ---------------- prep kernels ----------------
__global__ void pack_w(const float* __restrict__ Wa, int da,
                       const float* __restrict__ bi, const float* __restrict__ bh,
                       u16* __restrict__ Wout, float* __restrict__ bout)
{
    int total = 1024 * da;
    int gt = blockIdx.x * blockDim.x + threadIdx.x;
    int stride = gridDim.x * blockDim.x;
    for (int i = gt; i < total; i += stride) Wout[i] = f2bf(Wa[i]);
    if (bout && gt < 1024) bout[gt] = bi[gt] + bh[gt];
}

// fragment-ordered pack: unit u (16B) -> l=u&63, g=(u>>6)&3, kc, mem;
// row = g*256 + mem*16 + (l&15); k0 = kc*32 + (l>>4)*8;  K = 32*nkc = da+db
__global__ void pack_frag(const float* __restrict__ Wa, int da,
                          const float* __restrict__ Wb, int db,
                          int nkc, u16* __restrict__ out,
                          const float* __restrict__ bi, const float* __restrict__ bh,
                          float* __restrict__ bout)
{
    int total = 16 * nkc * 4 * 64;
    int gt = blockIdx.x * blockDim.x + threadIdx.x;
    int stride = gridDim.x * blockDim.x;
    for (int u = gt; u < total; u += stride) {
        int l = u & 63;
        int t1 = u >> 6;
        int g = t1 & 3;
        int t2 = t1 >> 2;
        int kc = t2 % nkc;
        int mem = t2 / nkc;
        int row = g * 256 + mem * 16 + (l & 15);
        int k0 = kc * 32 + ((l >> 4) << 3);
        u16x8 o;
#pragma unroll
        for (int j = 0; j < 8; ++j) {
            int k = k0 + j;
            float v = (k < da) ? Wa[(size_t)row * da + k] : Wb[(size_t)row * db + (k - da)];
            o[j] = f2bf(v);
        }
        *(u16x8*)(out + (size_t)u * 8) = o;
    }
    if (bout && gt < 1024) bout[gt] = bi[gt] + bh[gt];
}

// ---------------- final linear ----------------
__global__ void final_linear(const float* __restrict__ latent, const float* __restrict__ W3,
                             const float* __restrict__ b3, float* __restrict__ out)
{
    int idx = blockIdx.x * blockDim.x + threadIdx.x;
    if (idx >= BATCH * 10) return;
    int bb = idx / 10, c = idx - bb * 10;
    const float* lrow = latent + (size_t)bb * 512;
    const float* wrow = W3 + (size_t)c * 512;
    float s = b3[c];
#pragma unroll 4
    for (int k = 0; k < 512; k += 4) {
        float4 lv = *(const float4*)(lrow + k);
        float4 wv = *(const float4*)(wrow + k);
        s += lv.x * wv.x + lv.y * wv.y + lv.z * wv.z + lv.w * wv.w;
    }
    out[idx] = s;
}

// ---------------- launch ----------------
extern "C" void kernel_launch(void* const* d_in, const int* in_sizes, int n_in,
                              void* d_out, int out_size, void* d_ws, size_t ws_size,
                              hipStream_t stream)
{
    (void)in_sizes; (void)n_in; (void)out_size;
    if (ws_size < WS_NEED) return;   // leaves d_out poisoned -> diagnosable as ws shortfall

    const float* xs     = (const float*)d_in[0];
    const float* Wih_f0 = (const float*)d_in[1];
    const float* Whh_f0 = (const float*)d_in[2];
    const float* bih_f0 = (const float*)d_in[3];
    const float* bhh_f0 = (const float*)d_in[4];
    const float* Wih_f1 = (const float*)d_in[5];
    const float* Whh_f1 = (const float*)d_in[6];
    const float* bih_f1 = (const float*)d_in[7];
    const float* bhh_f1 = (const float*)d_in[8];
    const float* Wih_r0 = (const float*)d_in[9];
    const float* Whh_r0 = (const float*)d_in[10];
    const float* bih_r0 = (const float*)d_in[11];
    const float* bhh_r0 = (const float*)d_in[12];
    const float* Wih_r1 = (const float*)d_in[13];
    const float* Whh_r1 = (const float*)d_in[14];
    const float* bih_r1 = (const float*)d_in[15];
    const float* bhh_r1 = (const float*)d_in[16];
    const float* W3     = (const float*)d_in[17];
    const float* b3     = (const float*)d_in[18];

    char* ws = (char*)d_ws;
    unsigned* ctl = (unsigned*)(ws + OFF_CTL);
    unsigned* h0g = (unsigned*)(ws + OFF_H0G);
    unsigned* h1g = (unsigned*)(ws + OFF_H1G);
    float* latent = (float*)(ws + OFF_LAT);
    _Float16* xp  = (_Float16*)(ws + OFF_XP);
    u16* W0xf = (u16*)(ws + OFF_W0XF);
    u16* W0xr = (u16*)(ws + OFF_W0XR);
    u16* P0f  = (u16*)(ws + OFF_P0F);
    u16* P0r  = (u16*)(ws + OFF_P0R);
    u16* P1f  = (u16*)(ws + OFF_P1F);
    u16* P1r  = (u16*)(ws + OFF_P1R);
    float* bs0f = (float*)(ws + OFF_BS0F);
    float* bs0r = (float*)(ws + OFF_BS0R);
    float* bs1f = (float*)(ws + OFF_BS1F);
    float* bs1r = (float*)(ws + OFF_BS1R);

    hipMemsetAsync(ctl, 0, 4096, stream);   // flag lines only

    pack_w<<<256, 256, 0, stream>>>(Wih_f0, 512, bih_f0, bhh_f0, W0xf, bs0f);
    pack_w<<<256, 256, 0, stream>>>(Wih_r0, 512, bih_r0, bhh_r0, W0xr, bs0r);
    pack_frag<<<64, 256, 0, stream>>>(Whh_f0, 256, Whh_f0, 0, 8,  P0f, nullptr, nullptr, nullptr);
    pack_frag<<<64, 256, 0, stream>>>(Whh_r0, 256, Whh_r0, 0, 8,  P0r, nullptr, nullptr, nullptr);
    pack_frag<<<64, 256, 0, stream>>>(Wih_f1, 256, Whh_f1, 256, 16, P1f, bih_f1, bhh_f1, bs1f);
    pack_frag<<<64, 256, 0, stream>>>(Wih_r1, 256, Whh_r1, 256, 16, P1r, bih_r1, bhh_r1, bs1r);

    xproj_gemm<<<4480, 256, 0, stream>>>(xs, W0xf, W0xr, bs0f, bs0r, xp);

    lstm_seq<<<256, 256, 0, stream>>>(xp, P0f, P0r, P1f, P1r, bs1f, bs1r,
                                      h0g, h1g, latent, ctl);

    final_linear<<<80, 256, 0, stream>>>(latent, W3, b3, (float*)d_out);
}